// Round 5
// baseline (135.472 us; speedup 1.0000x reference)
//
#include <hip/hip_runtime.h>

// GraphConvBlock via bf16 MFMA implicit GEMM, v5.
// v4 -> v5: wave tile 64oc x 32pix -> 64oc x 64pix (4m x 4p), 256-thr blocks
// (4 waves, one output row per wave). Doubles FLOP per LDS byte (21->32).
// Everything else (layouts, swizzles, async weight dbuf, counted vmcnt) = v4.

typedef __bf16 bf16x8 __attribute__((ext_vector_type(8)));
typedef float f32x4 __attribute__((ext_vector_type(4)));

union U4 { uint4 u; bf16x8 b; };

__device__ inline unsigned pk_bf16(float lo, float hi) {
  unsigned r;
  asm volatile("v_cvt_pk_bf16_f32 %0, %1, %2" : "=v"(r) : "v"(lo), "v"(hi));
  return r;
}

__device__ inline unsigned addpk(unsigned a, unsigned b) {
  float alo = __builtin_bit_cast(float, a << 16);
  float ahi = __builtin_bit_cast(float, a & 0xFFFF0000u);
  float blo = __builtin_bit_cast(float, b << 16);
  float bhi = __builtin_bit_cast(float, b & 0xFFFF0000u);
  return pk_bf16(alo + blo, ahi + bhi);
}

__device__ inline uint4 addpk4(uint4 a, uint4 b) {
  return make_uint4(addpk(a.x, b.x), addpk(a.y, b.y), addpk(a.z, b.z), addpk(a.w, b.w));
}

__device__ __forceinline__ void gload16(const unsigned* g, unsigned* l) {
  __builtin_amdgcn_global_load_lds(
      (const __attribute__((address_space(1))) unsigned*)(g),
      (__attribute__((address_space(3))) unsigned*)(l), 16, 0, 0);
}

template <int N>
__device__ __forceinline__ void waitcnt_vm() {
  if constexpr (N == 0) asm volatile("s_waitcnt vmcnt(0)" ::: "memory");
  else if constexpr (N == 2) asm volatile("s_waitcnt vmcnt(2)" ::: "memory");
  else asm volatile("s_waitcnt vmcnt(4)" ::: "memory");
}

// ---------------- weight repack: fp32 OIHW -> swizzled bf16 chunks -----------
// stem: 18 chunks (ochalf*9+tap) of [64r][32w] at 0; node s: 18 chunks of
// [64r][64w] at 36864 + s*73728.  Wb[ch][r*W + j] = w(r, icpair = j^((r&7)<<2)).
#define WB_WORDS 479232
__global__ void repack_w(const float* __restrict__ W0,
                         const float* __restrict__ Wn,
                         unsigned* __restrict__ Wb) {
  unsigned gid = blockIdx.x * 256 + threadIdx.x;
  if (gid >= WB_WORDS) return;
  const float* src;
  int CIN, c, r, j;
  if (gid < 36864) {
    src = W0; CIN = 64;
    c = gid >> 11; int w = gid & 2047; r = w >> 5; j = w & 31;
  } else {
    unsigned g = gid - 36864;
    int s = g / 73728; unsigned r2 = g % 73728;
    src = Wn + (size_t)s * 147456; CIN = 128;
    c = r2 >> 12; int w = r2 & 4095; r = w >> 6; j = w & 63;
  }
  int ochalf = c / 9, tap = c % 9;
  int dy = tap / 3, dx = tap % 3;
  int icpair = j ^ ((r & 7) << 2);
  int oc = ochalf * 64 + r;
  size_t base = (((size_t)oc * CIN + 2 * icpair) * 3 + dy) * 3 + dx;
  Wb[gid] = pk_bf16(src[base], src[base + 9]);
}

// ---------------- zero halo rings --------------------------------------------
__global__ void zero_halos(unsigned* __restrict__ B0, unsigned* __restrict__ B1,
                           unsigned* __restrict__ B2, unsigned* __restrict__ T) {
  unsigned gid = blockIdx.x * 256 + threadIdx.x;
  if (gid >= 116480) return;
  unsigned* buf; int CW; unsigned u;
  if (gid < 99840) {
    buf = gid < 33280 ? B0 : (gid < 66560 ? B1 : B2);
    u = gid % 33280; CW = 64;
  } else {
    buf = T; u = gid - 99840; CW = 32;
  }
  int per_n = 65 * CW;
  int n = u / per_n;
  unsigned v = u % per_n;
  int pix = (v * 4) / CW, cw = (v * 4) % CW;
  int row, col;
  if (pix < 66) { row = 0; col = pix; }
  else if (pix < 132) { row = 65; col = pix - 66; }
  else if (pix < 196) { row = pix - 131; col = 0; }
  else { row = pix - 195; col = 65; }
  *(uint4*)&buf[((((size_t)n * 66 + row) * 66 + col) * CW) + cw] =
      make_uint4(0, 0, 0, 0);
}

// ---------------- transform x: fp32 NCHW -> bf16 padded swizzled (64ch) ------
__global__ void transform_x(const float* __restrict__ x, unsigned* __restrict__ T) {
  __shared__ float xl[64][65];
  int n = blockIdx.y, h = blockIdx.x, tid = threadIdx.x;
#pragma unroll
  for (int k = 0; k < 16; ++k) {
    int idx = tid + k * 256;
    int ic = idx >> 6, w = idx & 63;
    xl[w][ic] = x[(((size_t)n * 64 + ic) * 64 + h) * 64 + w];
  }
  __syncthreads();
#pragma unroll
  for (int k = 0; k < 8; ++k) {
    int idx = tid + k * 256;
    int w = idx >> 5, icp = idx & 31;
    unsigned v = pk_bf16(xl[w][icp * 2], xl[w][icp * 2 + 1]);
    int wp = w + 1;
    int pos = icp ^ ((wp & 7) << 2);
    T[(((size_t)n * 66 + (h + 1)) * 66 + wp) * 32 + pos] = v;
  }
}

// ---------------- main conv stage --------------------------------------------
// 256 thr = 4 waves; wave wr handles output row h0+wr, 64 oc x 64 cols
// (4m x 4p frags of 16x16, acc 64 VGPR). grid 256 = 2 ochalf x 8 n x 16 hq.
template <int CIN, bool DUAL, bool OUTF32>
__global__ __launch_bounds__(256, 1) void conv_stage(
    const unsigned* __restrict__ in0, const unsigned* __restrict__ in1,
    const unsigned* __restrict__ wb, const float* __restrict__ bias,
    float bmult, void* __restrict__ outp) {
  constexpr int WPP = CIN / 2;          // u32 words per pixel
  constexpr int CHW = 64 * WPP;         // words per weight chunk (full-K, 64 oc)
  constexpr int WL = CHW / 1024;        // global_load_lds per thread per chunk
  constexpr int ROWW = 66 * WPP;        // words per staged act row
  constexpr int ACTW = 6 * ROWW;
  constexpr int ACT_U4 = ACTW / 4;
  constexpr int AJ = (ACT_U4 + 255) / 256;
  constexpr int NKC = CIN / 32;

  __shared__ unsigned Alds[ACTW];
  __shared__ unsigned Wlds[2][CHW];

  const int tid = threadIdx.x;
  const int lane = tid & 63;
  const int wav = tid >> 6;             // 0..3 == output row within tile
  const int wr = wav;
  const int l15 = lane & 15, q = lane >> 4;
  const int bid = blockIdx.x;
  const int n = bid & 7;                // same-n -> same XCD (L2 locality)
  const int ochalf = (bid >> 3) & 1;
  const int hq = bid >> 4;              // 0..15
  const int h0 = hq * 4;

  const unsigned* wbase = wb + (size_t)ochalf * 9 * CHW;

  // ---- prologue: issue weight chunks 0,1 (async, direct to LDS) ----
#pragma unroll
  for (int s = 0; s < WL; ++s)
    gload16(wbase + s * 1024 + tid * 4, &Wlds[0][s * 1024 + wav * 256]);
#pragma unroll
  for (int s = 0; s < WL; ++s)
    gload16(wbase + CHW + s * 1024 + tid * 4, &Wlds[1][s * 1024 + wav * 256]);

  // ---- stage acts once (6 padded rows, fused child-sum) ----
  {
    const size_t abase = ((size_t)n * 66 + h0) * ROWW;
    const uint4* g0 = (const uint4*)(in0 + abase);
    const uint4* g1 = (const uint4*)(in1 + abase);
#pragma unroll
    for (int j = 0; j < AJ; ++j) {
      int i = tid + j * 256;
      if (i < ACT_U4) {
        uint4 v = g0[i];
        if (DUAL) v = addpk4(v, g1[i]);
        *(uint4*)&Alds[4 * i] = v;
      }
    }
  }
  __syncthreads();  // acts visible to all waves

  f32x4 acc[4][4];
#pragma unroll
  for (int m = 0; m < 4; ++m)
#pragma unroll
    for (int p = 0; p < 4; ++p) acc[m][p] = (f32x4)0.f;

#pragma unroll
  for (int t = 0; t < 9; ++t) {
    // chunk t landed? (steady state: chunk t+1's WL loads stay in flight)
    if (t < 8) waitcnt_vm<WL>();
    else waitcnt_vm<0>();
    __builtin_amdgcn_s_barrier();
    __builtin_amdgcn_sched_barrier(0);

    const unsigned* WB = Wlds[t & 1];
    const int dy = t / 3, dx = t % 3;
    const int arow = (wr + dy) * 66;

    __builtin_amdgcn_s_setprio(1);
#pragma unroll
    for (int kc = 0; kc < NKC; ++kc) {
      bf16x8 a[4];
#pragma unroll
      for (int m = 0; m < 4; ++m) {
        int r = m * 16 + l15;
        U4 u;
        u.u = *(const uint4*)&WB[r * WPP + ((kc * 16 + q * 4) ^ ((r & 7) << 2))];
        a[m] = u.b;
      }
      bf16x8 b[4];
#pragma unroll
      for (int p = 0; p < 4; ++p) {
        int col = p * 16 + l15 + dx;
        U4 u;
        u.u = *(const uint4*)&Alds[(arow + col) * WPP +
                                   ((kc * 16 + q * 4) ^ ((col & 7) << 2))];
        b[p] = u.b;
      }
#pragma unroll
      for (int m = 0; m < 4; ++m)
#pragma unroll
        for (int p = 0; p < 4; ++p)
          acc[m][p] =
              __builtin_amdgcn_mfma_f32_16x16x32_bf16(a[m], b[p], acc[m][p], 0, 0, 0);
    }
    __builtin_amdgcn_s_setprio(0);
    __builtin_amdgcn_sched_barrier(0);
    __builtin_amdgcn_s_barrier();
    __builtin_amdgcn_sched_barrier(0);

    if (t + 2 < 9) {
#pragma unroll
      for (int s = 0; s < WL; ++s)
        gload16(wbase + (size_t)(t + 2) * CHW + s * 1024 + tid * 4,
                &Wlds[t & 1][s * 1024 + wav * 256]);
    }
    __builtin_amdgcn_sched_barrier(0);
  }

  // ---- epilogue ----
  const int obase = ochalf * 64;
  if (OUTF32) {
    float* out = (float*)outp;
#pragma unroll
    for (int m = 0; m < 4; ++m) {
      int oc0 = obase + m * 16 + q * 4;
      float4 bb = *(const float4*)&bias[oc0];
#pragma unroll
      for (int p = 0; p < 4; ++p) {
        int w = p * 16 + l15;
#pragma unroll
        for (int j = 0; j < 4; ++j)
          out[(((size_t)n * 128 + oc0 + j) * 64 + (h0 + wr)) * 64 + w] =
              acc[m][p][j] + ((const float*)&bb)[j] * bmult;
      }
    }
  } else {
    unsigned* out = (unsigned*)outp;
#pragma unroll
    for (int m = 0; m < 4; ++m) {
      int oc0 = obase + m * 16 + q * 4;
      float4 bb = *(const float4*)&bias[oc0];
      int icp0 = oc0 >> 1;
#pragma unroll
      for (int p = 0; p < 4; ++p) {
        int w = p * 16 + l15;
        int wp = w + 1;
        unsigned lo = pk_bf16(acc[m][p][0] + bb.x * bmult, acc[m][p][1] + bb.y * bmult);
        unsigned hi = pk_bf16(acc[m][p][2] + bb.z * bmult, acc[m][p][3] + bb.w * bmult);
        int pos = icp0 ^ ((wp & 7) << 2);
        size_t base = (((size_t)n * 66 + (h0 + 1 + wr)) * 66 + wp) * 64;
        *(uint2*)&out[base + pos] = make_uint2(lo, hi);
      }
    }
  }
}

// ---------------- launch ------------------------------------------------------
extern "C" void kernel_launch(void* const* d_in, const int* in_sizes, int n_in,
                              void* d_out, int out_size, void* d_ws,
                              size_t ws_size, hipStream_t stream) {
  const float* x = (const float*)d_in[0];
  const float* W0 = (const float*)d_in[1];
  const float* b0 = (const float*)d_in[2];
  const float* Wn = (const float*)d_in[3];
  const float* bn = (const float*)d_in[4];

  const size_t ACTB = (size_t)8 * 66 * 66 * 64;  // words per 128-ch act buffer
  const size_t TW = (size_t)8 * 66 * 66 * 32;    // words for 64-ch stem input
  unsigned* B0 = (unsigned*)d_ws;
  unsigned* B1 = B0 + ACTB;
  unsigned* B2 = B1 + ACTB;
  unsigned* T = B2 + ACTB;
  unsigned* Wb = T + TW;

  zero_halos<<<455, 256, 0, stream>>>(B0, B1, B2, T);
  repack_w<<<WB_WORDS / 256, 256, 0, stream>>>(W0, Wn, Wb);
  transform_x<<<dim3(64, 8), 256, 0, stream>>>(x, T);

  dim3 grid(256), blk(256);
  const unsigned* Wnode = Wb + 36864;
  const size_t NW = 73728;  // words per node-stage weight block

  // stem: T -> B0
  conv_stage<64, false, false><<<grid, blk, 0, stream>>>(T, T, Wb, b0, 1.f, B0);
  // node1 {0}: B0 -> B1
  conv_stage<128, false, false><<<grid, blk, 0, stream>>>(B0, B0, Wnode, bn + 0, 1.f, B1);
  // node2 {0,1}: B0+B1 -> B2
  conv_stage<128, true, false><<<grid, blk, 0, stream>>>(B0, B1, Wnode + 1 * NW, bn + 128, 2.f, B2);
  // node3 {1,2}: B1+B2 -> B0
  conv_stage<128, true, false><<<grid, blk, 0, stream>>>(B1, B2, Wnode + 2 * NW, bn + 256, 2.f, B0);
  // node4 {2,3}: B2+B0 -> B1
  conv_stage<128, true, false><<<grid, blk, 0, stream>>>(B2, B0, Wnode + 3 * NW, bn + 384, 2.f, B1);
  // node5 {3,4}: B0+B1 -> B2
  conv_stage<128, true, false><<<grid, blk, 0, stream>>>(B0, B1, Wnode + 4 * NW, bn + 512, 2.f, B2);
  // node6 {4,5}: B1+B2 -> d_out (fp32 NCHW)
  conv_stage<128, true, true><<<grid, blk, 0, stream>>>(B1, B2, Wnode + 5 * NW, bn + 640, 2.f, d_out);

  (void)in_sizes; (void)n_in; (void)out_size; (void)ws_size;
}

// Round 6
// 115.262 us; speedup vs baseline: 1.1753x; 1.1753x over previous
//
#include <hip/hip_runtime.h>

// GraphConvBlock via bf16 MFMA implicit GEMM, v6.
// v4 -> v6: K-split wave pairs. 512thr/8 waves (2/SIMD), wave = 64oc x 64pix
// x K/2 (kh in {0,1}); f32 pair-reduction through LDS once per stage.
// Weight LDS 3-deep -> ONE barrier per tap-phase (gload t+2 targets the buffer
// retired before phase t's barrier). Layouts/swizzles/aux kernels = v4/v5.

typedef __bf16 bf16x8 __attribute__((ext_vector_type(8)));
typedef float f32x4 __attribute__((ext_vector_type(4)));

union U4 { uint4 u; bf16x8 b; };

__device__ inline unsigned pk_bf16(float lo, float hi) {
  unsigned r;
  asm volatile("v_cvt_pk_bf16_f32 %0, %1, %2" : "=v"(r) : "v"(lo), "v"(hi));
  return r;
}

__device__ inline unsigned addpk(unsigned a, unsigned b) {
  float alo = __builtin_bit_cast(float, a << 16);
  float ahi = __builtin_bit_cast(float, a & 0xFFFF0000u);
  float blo = __builtin_bit_cast(float, b << 16);
  float bhi = __builtin_bit_cast(float, b & 0xFFFF0000u);
  return pk_bf16(alo + blo, ahi + bhi);
}

__device__ inline uint4 addpk4(uint4 a, uint4 b) {
  return make_uint4(addpk(a.x, b.x), addpk(a.y, b.y), addpk(a.z, b.z), addpk(a.w, b.w));
}

__device__ __forceinline__ void gload16(const unsigned* g, unsigned* l) {
  __builtin_amdgcn_global_load_lds(
      (const __attribute__((address_space(1))) unsigned*)(g),
      (__attribute__((address_space(3))) unsigned*)(l), 16, 0, 0);
}

template <int N>
__device__ __forceinline__ void waitcnt_vm() {
  if constexpr (N == 0) asm volatile("s_waitcnt vmcnt(0)" ::: "memory");
  else if constexpr (N == 1) asm volatile("s_waitcnt vmcnt(1)" ::: "memory");
  else asm volatile("s_waitcnt vmcnt(2)" ::: "memory");
}

// ---------------- weight repack: fp32 OIHW -> swizzled bf16 chunks -----------
// stem: 18 chunks (ochalf*9+tap) of [64r][32w] at 0; node s: 18 chunks of
// [64r][64w] at 36864 + s*73728.  Wb[ch][r*W + j] = w(r, icpair = j^((r&7)<<2)).
#define WB_WORDS 479232
__global__ void repack_w(const float* __restrict__ W0,
                         const float* __restrict__ Wn,
                         unsigned* __restrict__ Wb) {
  unsigned gid = blockIdx.x * 256 + threadIdx.x;
  if (gid >= WB_WORDS) return;
  const float* src;
  int CIN, c, r, j;
  if (gid < 36864) {
    src = W0; CIN = 64;
    c = gid >> 11; int w = gid & 2047; r = w >> 5; j = w & 31;
  } else {
    unsigned g = gid - 36864;
    int s = g / 73728; unsigned r2 = g % 73728;
    src = Wn + (size_t)s * 147456; CIN = 128;
    c = r2 >> 12; int w = r2 & 4095; r = w >> 6; j = w & 63;
  }
  int ochalf = c / 9, tap = c % 9;
  int dy = tap / 3, dx = tap % 3;
  int icpair = j ^ ((r & 7) << 2);
  int oc = ochalf * 64 + r;
  size_t base = (((size_t)oc * CIN + 2 * icpair) * 3 + dy) * 3 + dx;
  Wb[gid] = pk_bf16(src[base], src[base + 9]);
}

// ---------------- zero halo rings --------------------------------------------
__global__ void zero_halos(unsigned* __restrict__ B0, unsigned* __restrict__ B1,
                           unsigned* __restrict__ B2, unsigned* __restrict__ T) {
  unsigned gid = blockIdx.x * 256 + threadIdx.x;
  if (gid >= 116480) return;
  unsigned* buf; int CW; unsigned u;
  if (gid < 99840) {
    buf = gid < 33280 ? B0 : (gid < 66560 ? B1 : B2);
    u = gid % 33280; CW = 64;
  } else {
    buf = T; u = gid - 99840; CW = 32;
  }
  int per_n = 65 * CW;
  int n = u / per_n;
  unsigned v = u % per_n;
  int pix = (v * 4) / CW, cw = (v * 4) % CW;
  int row, col;
  if (pix < 66) { row = 0; col = pix; }
  else if (pix < 132) { row = 65; col = pix - 66; }
  else if (pix < 196) { row = pix - 131; col = 0; }
  else { row = pix - 195; col = 65; }
  *(uint4*)&buf[((((size_t)n * 66 + row) * 66 + col) * CW) + cw] =
      make_uint4(0, 0, 0, 0);
}

// ---------------- transform x: fp32 NCHW -> bf16 padded swizzled (64ch) ------
__global__ void transform_x(const float* __restrict__ x, unsigned* __restrict__ T) {
  __shared__ float xl[64][65];
  int n = blockIdx.y, h = blockIdx.x, tid = threadIdx.x;
#pragma unroll
  for (int k = 0; k < 16; ++k) {
    int idx = tid + k * 256;
    int ic = idx >> 6, w = idx & 63;
    xl[w][ic] = x[(((size_t)n * 64 + ic) * 64 + h) * 64 + w];
  }
  __syncthreads();
#pragma unroll
  for (int k = 0; k < 8; ++k) {
    int idx = tid + k * 256;
    int w = idx >> 5, icp = idx & 31;
    unsigned v = pk_bf16(xl[w][icp * 2], xl[w][icp * 2 + 1]);
    int wp = w + 1;
    int pos = icp ^ ((wp & 7) << 2);
    T[(((size_t)n * 66 + (h + 1)) * 66 + wp) * 32 + pos] = v;
  }
}

// ---------------- main conv stage --------------------------------------------
// 512 thr = 8 waves = 4 wr x 2 kh. Wave: 64oc x 64pix (row h0+wr) x K/2 (kh).
// Pair (wr,kh=0/1) reduces via LDS. grid 256 = 2 ochalf x 8 n x 16 hq.
template <int CIN, bool DUAL, bool OUTF32>
__global__ __launch_bounds__(512, 2) void conv_stage(
    const unsigned* __restrict__ in0, const unsigned* __restrict__ in1,
    const unsigned* __restrict__ wb, const float* __restrict__ bias,
    float bmult, void* __restrict__ outp) {
  constexpr int WPP = CIN / 2;          // u32 words per pixel
  constexpr int CHW = 64 * WPP;         // words per weight chunk (full-K, 64 oc)
  constexpr int WL = CHW / 2048;        // gload_lds per thread per chunk (512t)
  constexpr int ROWW = 66 * WPP;        // words per staged act row
  constexpr int ACTW = 6 * ROWW;
  constexpr int ALDS_W = (ACTW > 16384) ? ACTW : 16384;  // also reduction buf
  constexpr int ACT_U4 = ACTW / 4;
  constexpr int AJ = (ACT_U4 + 511) / 512;
  constexpr int KCW = CIN / 64;         // kc iterations per kh

  __shared__ unsigned Alds[ALDS_W];
  __shared__ unsigned Wlds[3][CHW];

  const int tid = threadIdx.x;
  const int lane = tid & 63;
  const int wav = tid >> 6;             // 0..7
  const int wr = wav >> 1;              // output row 0..3
  const int kh = wav & 1;               // K half
  const int l15 = lane & 15, q = lane >> 4;
  const int bid = blockIdx.x;
  const int n = bid & 7;                // same-n -> same XCD (L2 locality)
  const int ochalf = (bid >> 3) & 1;
  const int hq = bid >> 4;              // 0..15
  const int h0 = hq * 4;

  const unsigned* wbase = wb + (size_t)ochalf * 9 * CHW;

  // ---- prologue: issue weight chunks 0,1 (async, direct to LDS) ----
#pragma unroll
  for (int s = 0; s < WL; ++s)
    gload16(wbase + s * 2048 + tid * 4, &Wlds[0][s * 2048 + wav * 256]);
#pragma unroll
  for (int s = 0; s < WL; ++s)
    gload16(wbase + CHW + s * 2048 + tid * 4, &Wlds[1][s * 2048 + wav * 256]);

  // ---- stage acts once (6 padded rows, fused child-sum) ----
  {
    const size_t abase = ((size_t)n * 66 + h0) * ROWW;
    const uint4* g0 = (const uint4*)(in0 + abase);
    const uint4* g1 = (const uint4*)(in1 + abase);
#pragma unroll
    for (int j = 0; j < AJ; ++j) {
      int i = tid + j * 512;
      if (i < ACT_U4) {
        uint4 v = g0[i];
        if (DUAL) v = addpk4(v, g1[i]);
        *(uint4*)&Alds[4 * i] = v;
      }
    }
  }
  __syncthreads();  // acts visible to all waves

  f32x4 acc[4][4];
#pragma unroll
  for (int m = 0; m < 4; ++m)
#pragma unroll
    for (int p = 0; p < 4; ++p) acc[m][p] = (f32x4)0.f;

#pragma unroll
  for (int t = 0; t < 9; ++t) {
    if (t < 8) waitcnt_vm<WL>();
    else waitcnt_vm<0>();
    __builtin_amdgcn_s_barrier();      // chunk t visible from all waves
    __builtin_amdgcn_sched_barrier(0);

    const unsigned* WB = Wlds[t % 3];
    const int dy = t / 3, dx = t % 3;
    const int arow = (wr + dy) * 66;

    __builtin_amdgcn_s_setprio(1);
#pragma unroll
    for (int kc2 = 0; kc2 < KCW; ++kc2) {
      const int kc = kh * KCW + kc2;
      bf16x8 a[4];
#pragma unroll
      for (int m = 0; m < 4; ++m) {
        int r = m * 16 + l15;
        U4 u;
        u.u = *(const uint4*)&WB[r * WPP + ((kc * 16 + q * 4) ^ ((r & 7) << 2))];
        a[m] = u.b;
      }
      bf16x8 b[4];
#pragma unroll
      for (int p = 0; p < 4; ++p) {
        int col = p * 16 + l15 + dx;
        U4 u;
        u.u = *(const uint4*)&Alds[(arow + col) * WPP +
                                   ((kc * 16 + q * 4) ^ ((col & 7) << 2))];
        b[p] = u.b;
      }
#pragma unroll
      for (int m = 0; m < 4; ++m)
#pragma unroll
        for (int p = 0; p < 4; ++p)
          acc[m][p] =
              __builtin_amdgcn_mfma_f32_16x16x32_bf16(a[m], b[p], acc[m][p], 0, 0, 0);
    }
    __builtin_amdgcn_s_setprio(0);
    __builtin_amdgcn_sched_barrier(0);

    // issue chunk t+2 into buffer (t+2)%3 == (t-1)%3, whose readers finished
    // before THIS phase's barrier -> race-free with a single barrier/phase.
    if (t + 2 < 9) {
#pragma unroll
      for (int s = 0; s < WL; ++s)
        gload16(wbase + (size_t)(t + 2) * CHW + s * 2048 + tid * 4,
                &Wlds[(t + 2) % 3][s * 2048 + wav * 256]);
    }
    __builtin_amdgcn_sched_barrier(0);
  }

  // ---- K-pair reduction through LDS (reuse Alds; acts dead) ----
  __syncthreads();  // all phase-8 LDS reads done before overwrite
  float* R = (float*)Alds;
  if (kh) {
#pragma unroll
    for (int m = 0; m < 4; ++m)
#pragma unroll
      for (int p = 0; p < 4; ++p)
        *(f32x4*)&R[(wr * 16 + m * 4 + p) * 256 + lane * 4] = acc[m][p];
  }
  __syncthreads();
  if (kh) return;
#pragma unroll
  for (int m = 0; m < 4; ++m)
#pragma unroll
    for (int p = 0; p < 4; ++p) {
      f32x4 o = *(const f32x4*)&R[(wr * 16 + m * 4 + p) * 256 + lane * 4];
      acc[m][p] += o;
    }

  // ---- epilogue (kh==0 waves) ----
  const int obase = ochalf * 64;
  if (OUTF32) {
    float* out = (float*)outp;
#pragma unroll
    for (int m = 0; m < 4; ++m) {
      int oc0 = obase + m * 16 + q * 4;
      float4 bb = *(const float4*)&bias[oc0];
#pragma unroll
      for (int p = 0; p < 4; ++p) {
        int w = p * 16 + l15;
#pragma unroll
        for (int j = 0; j < 4; ++j)
          out[(((size_t)n * 128 + oc0 + j) * 64 + (h0 + wr)) * 64 + w] =
              acc[m][p][j] + ((const float*)&bb)[j] * bmult;
      }
    }
  } else {
    unsigned* out = (unsigned*)outp;
#pragma unroll
    for (int m = 0; m < 4; ++m) {
      int oc0 = obase + m * 16 + q * 4;
      float4 bb = *(const float4*)&bias[oc0];
      int icp0 = oc0 >> 1;
#pragma unroll
      for (int p = 0; p < 4; ++p) {
        int w = p * 16 + l15;
        int wp = w + 1;
        unsigned lo = pk_bf16(acc[m][p][0] + bb.x * bmult, acc[m][p][1] + bb.y * bmult);
        unsigned hi = pk_bf16(acc[m][p][2] + bb.z * bmult, acc[m][p][3] + bb.w * bmult);
        int pos = icp0 ^ ((wp & 7) << 2);
        size_t base = (((size_t)n * 66 + (h0 + 1 + wr)) * 66 + wp) * 64;
        *(uint2*)&out[base + pos] = make_uint2(lo, hi);
      }
    }
  }
}

// ---------------- launch ------------------------------------------------------
extern "C" void kernel_launch(void* const* d_in, const int* in_sizes, int n_in,
                              void* d_out, int out_size, void* d_ws,
                              size_t ws_size, hipStream_t stream) {
  const float* x = (const float*)d_in[0];
  const float* W0 = (const float*)d_in[1];
  const float* b0 = (const float*)d_in[2];
  const float* Wn = (const float*)d_in[3];
  const float* bn = (const float*)d_in[4];

  const size_t ACTB = (size_t)8 * 66 * 66 * 64;  // words per 128-ch act buffer
  const size_t TW = (size_t)8 * 66 * 66 * 32;    // words for 64-ch stem input
  unsigned* B0 = (unsigned*)d_ws;
  unsigned* B1 = B0 + ACTB;
  unsigned* B2 = B1 + ACTB;
  unsigned* T = B2 + ACTB;
  unsigned* Wb = T + TW;

  zero_halos<<<455, 256, 0, stream>>>(B0, B1, B2, T);
  repack_w<<<WB_WORDS / 256, 256, 0, stream>>>(W0, Wn, Wb);
  transform_x<<<dim3(64, 8), 256, 0, stream>>>(x, T);

  dim3 grid(256), blk(512);
  const unsigned* Wnode = Wb + 36864;
  const size_t NW = 73728;  // words per node-stage weight block

  // stem: T -> B0
  conv_stage<64, false, false><<<grid, blk, 0, stream>>>(T, T, Wb, b0, 1.f, B0);
  // node1 {0}: B0 -> B1
  conv_stage<128, false, false><<<grid, blk, 0, stream>>>(B0, B0, Wnode, bn + 0, 1.f, B1);
  // node2 {0,1}: B0+B1 -> B2
  conv_stage<128, true, false><<<grid, blk, 0, stream>>>(B0, B1, Wnode + 1 * NW, bn + 128, 2.f, B2);
  // node3 {1,2}: B1+B2 -> B0
  conv_stage<128, true, false><<<grid, blk, 0, stream>>>(B1, B2, Wnode + 2 * NW, bn + 256, 2.f, B0);
  // node4 {2,3}: B2+B0 -> B1
  conv_stage<128, true, false><<<grid, blk, 0, stream>>>(B2, B0, Wnode + 3 * NW, bn + 384, 2.f, B1);
  // node5 {3,4}: B0+B1 -> B2
  conv_stage<128, true, false><<<grid, blk, 0, stream>>>(B0, B1, Wnode + 4 * NW, bn + 512, 2.f, B2);
  // node6 {4,5}: B1+B2 -> d_out (fp32 NCHW)
  conv_stage<128, true, true><<<grid, blk, 0, stream>>>(B1, B2, Wnode + 5 * NW, bn + 640, 2.f, d_out);

  (void)in_sizes; (void)n_in; (void)out_size; (void)ws_size;
}